// Round 7
// baseline (1340.891 us; speedup 1.0000x reference)
//
#include <hip/hip_runtime.h>

#define NN 100000
#define NE 1600000
#define DD 128
#define CAP 64      // padded-CSR capacity; P(Poisson(16) >= 64) ~ 1e-19
#define NGROUP 256  // edge-slice groups for filtered scatter

// ---------- bf16 helpers (manual, RNE) ----------
static __device__ __forceinline__ unsigned short f2b(float f) {
  unsigned int x = __float_as_uint(f);
  unsigned int r = x + 0x7fffu + ((x >> 16) & 1u);
  return (unsigned short)(r >> 16);
}
static __device__ __forceinline__ float b2f(unsigned short u) {
  return __uint_as_float(((unsigned int)u) << 16);
}

typedef __attribute__((ext_vector_type(8))) short short8;
typedef __attribute__((ext_vector_type(4))) float f32x4;
typedef unsigned int v4u __attribute__((ext_vector_type(4)));

union V8 {
  uint4 u4;
  v4u v4;
  short8 s8;
  unsigned short us[8];
};

// ---------- edge-index dtype detector ----------
__global__ void detect_k(const int* __restrict__ ei, int* __restrict__ flag) {
  int v = ei[2 * threadIdx.x + 1];
  unsigned long long b = __ballot(v != 0);
  if (threadIdx.x == 0) *flag = (b == 0ull) ? 1 : 0;
}

// ---------- fp32 -> bf16 cast into column-sharded layout xc[8][NN][16] ----------
// blockIdx.y = group g. Thread n reads x[n][g*16..g*16+16] (one 64B line) and
// writes 32B contiguous at xc[g][n].
__global__ __launch_bounds__(256) void cast_k(const float* __restrict__ x,
                                              unsigned short* __restrict__ xc) {
  const int g = blockIdx.y;
  const int n = blockIdx.x * 256 + threadIdx.x;
  if (n >= NN) return;
  const float* xp = x + (size_t)n * DD + g * 16;
  V8 o0, o1;
#pragma unroll
  for (int j = 0; j < 4; ++j) {
    o0.us[j] = f2b(xp[j]);
    o0.us[4 + j] = f2b(xp[4 + j]);
    o1.us[j] = f2b(xp[8 + j]);
    o1.us[4 + j] = f2b(xp[12 + j]);
  }
  unsigned short* op = xc + ((size_t)g * NN + n) * 16;
  *(uint4*)op = o0.u4;
  *(uint4*)(op + 8) = o1.u4;
}

// ---------- pack edges to (src,dst) int pairs + zero cnt ----------
__global__ __launch_bounds__(256) void pack_k(const int* __restrict__ ei,
                                              int* __restrict__ packed,  // [NE][2]
                                              int* __restrict__ cnt,
                                              const int* __restrict__ flag) {
  const int mode = *flag;
  const int gid = blockIdx.x * 256 + threadIdx.x;
  int s, d;
  if (mode) {  // int64 little-endian, values < 2^31: low word at even offset
    s = ei[2 * (size_t)gid];
    d = ei[2 * ((size_t)NE + gid)];
  } else {
    s = ei[gid];
    d = ei[NE + gid];
  }
  packed[2 * gid] = s;
  packed[2 * gid + 1] = d;
  if (gid < NN) cnt[gid] = 0;
}

// ---------- padded-CSR scatter, XCD-range-filtered ----------
__global__ __launch_bounds__(256) void scatter_k(const long long* __restrict__ packed,
                                                 int* __restrict__ cnt,
                                                 int* __restrict__ csr) {
  const int r = blockIdx.x & 7;
  const int g = blockIdx.x >> 3;
  const int lo = r * (NN / 8), hi = lo + (NN / 8);
  for (int e = g * 256 + threadIdx.x; e < NE; e += NGROUP * 256) {
    long long sd = __builtin_nontemporal_load(&packed[e]);
    const int s = (int)(sd & 0xffffffffll);
    const int d = (int)(sd >> 32);
    if (d >= lo && d < hi) {
      int c = atomicAdd(&cnt[d], 1);
      if (c < CAP) csr[(size_t)d * CAP + c] = s;
    }
  }
}

// ---------- degree counting sort (wave-divergence killer for agg_k) ----------
__global__ __launch_bounds__(256) void hist2_k(const int* __restrict__ cnt,
                                               int* __restrict__ dbin) {
  __shared__ int lb[CAP + 1];
  if (threadIdx.x <= CAP) lb[threadIdx.x] = 0;
  __syncthreads();
  const int i = blockIdx.x * 256 + threadIdx.x;
  if (i < NN) atomicAdd(&lb[min(cnt[i], CAP)], 1);
  __syncthreads();
  if (threadIdx.x <= CAP && lb[threadIdx.x]) atomicAdd(&dbin[threadIdx.x], lb[threadIdx.x]);
}

__global__ void dscan_k(const int* __restrict__ dbin, int* __restrict__ dcur) {
  if (threadIdx.x == 0) {
    int run = 0;
    for (int i = 0; i <= CAP; ++i) {
      dcur[i] = run;
      run += dbin[i];
    }
  }
}

__global__ __launch_bounds__(256) void dorder_k(const int* __restrict__ cnt,
                                                int* __restrict__ dcur,
                                                int* __restrict__ order) {
  const int i = blockIdx.x * 256 + threadIdx.x;
  if (i < NN) {
    int c = min(cnt[i], CAP);
    int pos = atomicAdd(&dcur[c], 1);
    order[pos] = i | (c << 24);  // node in low 24 bits, degree in high bits
  }
}

// ---------- weight prep: transpose+cast all 7 matrices to bf16 wT[n][k] ----------
__global__ __launch_bounds__(256) void wprep_k(const float* __restrict__ W1,
                                               const float* __restrict__ W2,
                                               const float* __restrict__ fW1,
                                               const float* __restrict__ fW2,
                                               unsigned short* __restrict__ wt) {
  int b = blockIdx.x;
  const float* src;
  int moff, N;
  if (b < 192) {
    int m = b >> 6;
    src = W1 + m * 16384;
    moff = m * 16384;
    N = 128;
    b &= 63;
  } else if (b < 384) {
    int m = (b - 192) >> 6;
    src = W2 + m * 16384;
    moff = (3 + m) * 16384;
    N = 128;
    b = (b - 192) & 63;
  } else if (b < 448) {
    src = fW1;
    moff = 6 * 16384;
    N = 128;
    b -= 384;
  } else {
    src = fW2;
    moff = 7 * 16384;
    N = 64;
    b -= 448;
  }
  int idx = b * 256 + threadIdx.x;  // n*128 + k
  int n = idx >> 7, k = idx & 127;
  if (n < N) wt[moff + idx] = f2b(src[(size_t)k * N + n]);
}

// ---------- column-sharded aggregation: hc[g][n] = xc[g][n] + sum_{s in in(n)} xc[g][s] ----------
// Group g pinned to XCD g via blockIdx&7: each XCD's random gathers hit its own
// L2-resident 3.2MB slice. 1 lane per node (degree-sorted order -> uniform waves).
__global__ __launch_bounds__(256) void agg_k(const int* __restrict__ order,
                                             const int* __restrict__ csr,
                                             const unsigned short* __restrict__ xc,
                                             unsigned short* __restrict__ hc) {
  const int g = blockIdx.x & 7;
  const unsigned short* xg = xc + (size_t)g * NN * 16;
  unsigned short* hg = hc + (size_t)g * NN * 16;
  const int stride = (gridDim.x >> 3) * 256;
  for (int i = (blockIdx.x >> 3) * 256 + threadIdx.x; i < NN; i += stride) {
    const int oc = order[i];
    const int n = oc & 0xFFFFFF;
    const int c = oc >> 24;
    V8 v0, v1;
    v0.u4 = *(const uint4*)(xg + (size_t)n * 16);
    v1.u4 = *(const uint4*)(xg + (size_t)n * 16 + 8);
    float acc[16];
#pragma unroll
    for (int j = 0; j < 8; ++j) {
      acc[j] = b2f(v0.us[j]);
      acc[8 + j] = b2f(v1.us[j]);
    }
    const int* row = csr + (size_t)n * CAP;
    int p = 0;
    for (; p + 2 <= c; p += 2) {
      const int s0 = row[p], s1 = row[p + 1];
      V8 a0, a1, b0, b1;
      a0.u4 = *(const uint4*)(xg + (size_t)s0 * 16);
      a1.u4 = *(const uint4*)(xg + (size_t)s0 * 16 + 8);
      b0.u4 = *(const uint4*)(xg + (size_t)s1 * 16);
      b1.u4 = *(const uint4*)(xg + (size_t)s1 * 16 + 8);
#pragma unroll
      for (int j = 0; j < 8; ++j) {
        acc[j] += b2f(a0.us[j]) + b2f(b0.us[j]);
        acc[8 + j] += b2f(a1.us[j]) + b2f(b1.us[j]);
      }
    }
    if (p < c) {
      const int s0 = row[p];
      V8 a0, a1;
      a0.u4 = *(const uint4*)(xg + (size_t)s0 * 16);
      a1.u4 = *(const uint4*)(xg + (size_t)s0 * 16 + 8);
#pragma unroll
      for (int j = 0; j < 8; ++j) {
        acc[j] += b2f(a0.us[j]);
        acc[8 + j] += b2f(a1.us[j]);
      }
    }
    V8 o0, o1;
#pragma unroll
    for (int j = 0; j < 8; ++j) {
      o0.us[j] = f2b(acc[j]);
      o1.us[j] = f2b(acc[8 + j]);
    }
    // nt stores: don't let dirty hc lines evict the xg slice from L2
    __builtin_nontemporal_store(o0.v4, (v4u*)(hg + (size_t)n * 16));
    __builtin_nontemporal_store(o1.v4, (v4u*)(hg + (size_t)n * 16 + 8));
  }
}

// ---------- MFMA GEMM: C[M x NCOLS] = A[M x 128] @ wT^T + bias ----------
// AMODE: 1 = A bf16 column-sharded [8][NN][16] plain,
//        2 = A bf16 row-major + BN(scale,shift from raw stats)+ReLU
// EPI:   0 = store bf16 row-major, 2 = store fp32 row-major,
//        3 = relu + store bf16 column-sharded
// STATS: 1 = accumulate per-column sum/sumsq of the (rounded) output into stats_out
template <int AMODE, int NCOLS, int EPI, int STATS>
__global__ __launch_bounds__(256) void gemm_k(const unsigned short* __restrict__ Aptr,
                                              const unsigned short* __restrict__ wT,
                                              const float* __restrict__ bias,
                                              const float* __restrict__ bn_stats,
                                              const float* __restrict__ gamma,
                                              const float* __restrict__ beta,
                                              void* __restrict__ Cptr,
                                              float* __restrict__ stats_out) {
  __shared__ unsigned short bT[NCOLS][136];
  __shared__ float biasS[NCOLS];
  __shared__ float scS[128];
  __shared__ float shS[128];
  __shared__ float sS[NCOLS];
  __shared__ float s2S[NCOLS];
  const int tid = threadIdx.x;

  for (int i = tid; i < NCOLS * 16; i += 256) {
    int n = i >> 4, k8 = (i & 15) << 3;
    *(uint4*)&bT[n][k8] = *(const uint4*)(wT + n * 128 + k8);
  }
  if (tid < NCOLS) biasS[tid] = bias[tid];
  if (AMODE == 2 && tid < 128) {
    const float inv_n = 1.0f / (float)NN;
    float mu = bn_stats[tid] * inv_n;
    float var = bn_stats[128 + tid] * inv_n - mu * mu;
    float sc = gamma[tid] * rsqrtf(var + 1e-5f);
    scS[tid] = sc;
    shS[tid] = beta[tid] - mu * sc;
  }
  if (STATS && tid < NCOLS) {
    sS[tid] = 0.f;
    s2S[tid] = 0.f;
  }
  __syncthreads();

  const int wv = tid >> 6;
  const int lane = tid & 63;
  const int l16 = lane & 15;
  const int quad = lane >> 4;
  const int arow = blockIdx.x * 64 + wv * 16 + l16;  // A row (m = lane&15)
  const bool rv = arow < NN;

  V8 afs[4];
#pragma unroll
  for (int kc = 0; kc < 4; ++kc) {
    if (AMODE == 1) {
      const int col8 = kc * 4 + quad;  // 16-byte chunk index in the 256B row
      const unsigned short* ap =
          Aptr + ((size_t)(col8 >> 1) * NN + arow) * 16 + (col8 & 1) * 8;
      afs[kc].u4 = rv ? *(const uint4*)ap : make_uint4(0u, 0u, 0u, 0u);
    } else {
      const int k0 = kc * 32 + quad * 8;
      afs[kc].u4 = rv ? *(const uint4*)(Aptr + (size_t)arow * DD + k0)
                      : make_uint4(0u, 0u, 0u, 0u);
#pragma unroll
      for (int j = 0; j < 8; ++j) {
        float f = fmaf(b2f(afs[kc].us[j]), scS[k0 + j], shS[k0 + j]);
        afs[kc].us[j] = f2b(fmaxf(f, 0.0f));
      }
    }
  }

  f32x4 acc[NCOLS / 16];
#pragma unroll
  for (int nt = 0; nt < NCOLS / 16; ++nt) acc[nt] = (f32x4)(0.0f);
#pragma unroll
  for (int kc = 0; kc < 4; ++kc) {
    const int k0 = kc * 32 + quad * 8;
#pragma unroll
    for (int nt = 0; nt < NCOLS / 16; ++nt) {
      V8 bf;
      bf.u4 = *(const uint4*)&bT[nt * 16 + l16][k0];
      acc[nt] = __builtin_amdgcn_mfma_f32_16x16x32_bf16(afs[kc].s8, bf.s8, acc[nt], 0, 0, 0);
    }
  }

  // C/D layout: col = lane&15, row = quad*4 + reg
  const int r0 = blockIdx.x * 64 + wv * 16 + quad * 4;
#pragma unroll
  for (int nt = 0; nt < NCOLS / 16; ++nt) {
    const int col = nt * 16 + l16;
    const float bv = biasS[col];
    float s = 0.f, s2 = 0.f;
#pragma unroll
    for (int i = 0; i < 4; ++i) {
      const int r = r0 + i;
      if (r < NN) {
        float v = acc[nt][i] + bv;
        if (EPI == 2) {
          ((float*)Cptr)[(size_t)r * NCOLS + col] = v;
        } else if (EPI == 3) {
          v = fmaxf(v, 0.0f);
          ((unsigned short*)Cptr)[((size_t)nt * NN + r) * 16 + l16] = f2b(v);
        } else {
          unsigned short us = f2b(v);
          ((unsigned short*)Cptr)[(size_t)r * NCOLS + col] = us;
          if (STATS) {
            float vr = b2f(us);  // stats on rounded value (matches gemm2's input)
            s += vr;
            s2 += vr * vr;
          }
        }
      }
    }
    if (STATS) {
      s += __shfl_xor(s, 16);
      s += __shfl_xor(s, 32);
      s2 += __shfl_xor(s2, 16);
      s2 += __shfl_xor(s2, 32);
      if (quad == 0) {
        atomicAdd(&sS[col], s);
        atomicAdd(&s2S[col], s2);
      }
    }
  }
  if (STATS) {
    __syncthreads();
    if (tid < NCOLS) {
      atomicAdd(&stats_out[tid], sS[tid]);
      atomicAdd(&stats_out[128 + tid], s2S[tid]);
    }
  }
}

// ---------- launch ----------
extern "C" void kernel_launch(void* const* d_in, const int* in_sizes, int n_in,
                              void* d_out, int out_size, void* d_ws, size_t ws_size,
                              hipStream_t stream) {
  const float* x = (const float*)d_in[0];
  const int* ei = (const int*)d_in[1];
  const float* W1 = (const float*)d_in[2];
  const float* b1 = (const float*)d_in[3];
  const float* g1 = (const float*)d_in[4];
  const float* be1 = (const float*)d_in[5];
  const float* W2 = (const float*)d_in[6];
  const float* b2 = (const float*)d_in[7];
  const float* fW1 = (const float*)d_in[8];
  const float* fb1 = (const float*)d_in[9];
  const float* fg1 = (const float*)d_in[10];
  const float* fbe1 = (const float*)d_in[11];
  const float* fW2 = (const float*)d_in[12];
  const float* fb2 = (const float*)d_in[13];

  char* ws = (char*)d_ws;
  unsigned short* xc = (unsigned short*)ws;                       // 25.6 MB col-sharded
  unsigned short* t16 = (unsigned short*)(ws + (size_t)25600000); // 25.6 MB row-major
  int* packed = (int*)t16;  // 12.8 MB, consumed by scatter before t16 is written
  int* csr = (int*)(ws + (size_t)51200000);    // NN*CAP*4 = 25.6 MB
  int* cnt = (int*)(ws + (size_t)76800000);    // 400 KB
  int* order = (int*)(ws + (size_t)77200000);  // 400 KB
  char* smallz = ws + (size_t)77600000;        // zeroed 8 KB block
  int* dbin = (int*)smallz;
  int* dcur = (int*)(smallz + 1024);
  float* stats4 = (float*)(smallz + 2048);  // 4 x 256 f
  int* flag = (int*)(ws + (size_t)77608192);
  unsigned short* wt = (unsigned short*)(ws + (size_t)77610240);  // 256 KB
  unsigned short* hc = (unsigned short*)d_out;  // 25.6 MB scratch until final store

  const int gemmBlocks = (NN + 63) / 64;   // 1563
  const int edgeBlocks = NE / 256;         // 6250
  const int nodeBlocks = (NN + 255) / 256; // 391
  const int filtBlocks = NGROUP * 8;       // 2048

  detect_k<<<1, 64, 0, stream>>>(ei, flag);
  (void)hipMemsetAsync(smallz, 0, 8192, stream);
  cast_k<<<dim3(nodeBlocks, 8), 256, 0, stream>>>(x, xc);
  pack_k<<<edgeBlocks, 256, 0, stream>>>(ei, packed, cnt, flag);
  wprep_k<<<480, 256, 0, stream>>>(W1, W2, fW1, fW2, wt);
  scatter_k<<<filtBlocks, 256, 0, stream>>>((const long long*)packed, cnt, csr);
  hist2_k<<<nodeBlocks, 256, 0, stream>>>(cnt, dbin);
  dscan_k<<<1, 64, 0, stream>>>(dbin, dcur);
  dorder_k<<<nodeBlocks, 256, 0, stream>>>(cnt, dcur, order);

  for (int l = 0; l < 3; ++l) {
    agg_k<<<1024, 256, 0, stream>>>(order, csr, xc, hc);
    gemm_k<1, 128, 0, 1><<<gemmBlocks, 256, 0, stream>>>(
        hc, wt + (size_t)l * 16384, b1 + l * 128, nullptr, nullptr, nullptr, t16,
        stats4 + l * 256);
    gemm_k<2, 128, 3, 0><<<gemmBlocks, 256, 0, stream>>>(
        t16, wt + (size_t)(3 + l) * 16384, b2 + l * 128, stats4 + l * 256,
        g1 + l * 128, be1 + l * 128, xc, nullptr);
  }

  // final MLP: Linear -> BN -> ReLU -> Linear, out fp32 [NN x 64]
  gemm_k<1, 128, 0, 1><<<gemmBlocks, 256, 0, stream>>>(
      xc, wt + (size_t)6 * 16384, fb1, nullptr, nullptr, nullptr, t16,
      stats4 + 3 * 256);
  gemm_k<2, 64, 2, 0><<<gemmBlocks, 256, 0, stream>>>(
      t16, wt + (size_t)7 * 16384, fb2, stats4 + 3 * 256, fg1, fbe1, (float*)d_out,
      nullptr);
}

// Round 8
// 675.252 us; speedup vs baseline: 1.9858x; 1.9858x over previous
//
#include <hip/hip_runtime.h>

#define NN 100000
#define NE 1600000
#define DD 128
#define CAP 64      // padded-CSR capacity; P(Poisson(16) >= 64) ~ 1e-19
#define NGROUP 256  // edge-slice groups for filtered scatter
#define TILES ((NN + 63) / 64)  // 1563 row-tiles of 64
#define GEMMGRID 521            // 521 * 3 = 1563 -> exactly 3 tiles/block

// ---------- bf16 helpers (manual, RNE) ----------
static __device__ __forceinline__ unsigned short f2b(float f) {
  unsigned int x = __float_as_uint(f);
  unsigned int r = x + 0x7fffu + ((x >> 16) & 1u);
  return (unsigned short)(r >> 16);
}
static __device__ __forceinline__ float b2f(unsigned short u) {
  return __uint_as_float(((unsigned int)u) << 16);
}

typedef __attribute__((ext_vector_type(8))) short short8;
typedef __attribute__((ext_vector_type(4))) float f32x4;
typedef unsigned int v4u __attribute__((ext_vector_type(4)));

union V8 {
  uint4 u4;
  v4u v4;
  short8 s8;
  unsigned short us[8];
};

// ---------- edge-index dtype detector ----------
__global__ void detect_k(const int* __restrict__ ei, int* __restrict__ flag) {
  int v = ei[2 * threadIdx.x + 1];
  unsigned long long b = __ballot(v != 0);
  if (threadIdx.x == 0) *flag = (b == 0ull) ? 1 : 0;
}

// ---------- fp32 -> bf16 cast (x input), row-major ----------
__global__ __launch_bounds__(256) void cast_k(const float* __restrict__ x,
                                              unsigned short* __restrict__ x16) {
  size_t i = ((size_t)blockIdx.x * 256 + threadIdx.x) * 8;
  f32x4 a = *(const f32x4*)(x + i);
  f32x4 b = *(const f32x4*)(x + i + 4);
  V8 v;
#pragma unroll
  for (int j = 0; j < 4; ++j) {
    v.us[j] = f2b(a[j]);
    v.us[4 + j] = f2b(b[j]);
  }
  *(uint4*)(x16 + i) = v.u4;
}

// ---------- pack edges to (src,dst) int pairs + zero cnt ----------
__global__ __launch_bounds__(256) void pack_k(const int* __restrict__ ei,
                                              int* __restrict__ packed,  // [NE][2]
                                              int* __restrict__ cnt,
                                              const int* __restrict__ flag) {
  const int mode = *flag;
  const int gid = blockIdx.x * 256 + threadIdx.x;
  int s, d;
  if (mode) {  // int64 little-endian, values < 2^31: low word at even offset
    s = ei[2 * (size_t)gid];
    d = ei[2 * ((size_t)NE + gid)];
  } else {
    s = ei[gid];
    d = ei[NE + gid];
  }
  packed[2 * gid] = s;
  packed[2 * gid + 1] = d;
  if (gid < NN) cnt[gid] = 0;
}

// ---------- padded-CSR scatter, XCD-range-filtered ----------
// blockIdx&7 selects a dst range; same-range blocks land on the same XCD
// (blockIdx%8 round-robin) -> cnt/csr lines written by one XCD only.
// packed read non-temporally so the 12.8MB stream doesn't evict dirty csr/cnt.
__global__ __launch_bounds__(256) void scatter_k(const long long* __restrict__ packed,
                                                 int* __restrict__ cnt,
                                                 int* __restrict__ csr) {
  const int r = blockIdx.x & 7;
  const int g = blockIdx.x >> 3;
  const int lo = r * (NN / 8), hi = lo + (NN / 8);
  for (int e = g * 256 + threadIdx.x; e < NE; e += NGROUP * 256) {
    long long sd = __builtin_nontemporal_load(&packed[e]);
    const int s = (int)(sd & 0xffffffffll);
    const int d = (int)(sd >> 32);
    if (d >= lo && d < hi) {
      int c = atomicAdd(&cnt[d], 1);
      if (c < CAP) csr[(size_t)d * CAP + c] = s;
    }
  }
}

// ---------- weight prep: transpose+cast all 7 matrices to bf16 wT[n][k] ----------
// seg m (16384 shorts each): 0-2 = W1[l], 3-5 = W2[l], 6 = fW1, 7 = fW2 (64x128).
__global__ __launch_bounds__(256) void wprep_k(const float* __restrict__ W1,
                                               const float* __restrict__ W2,
                                               const float* __restrict__ fW1,
                                               const float* __restrict__ fW2,
                                               unsigned short* __restrict__ wt) {
  int b = blockIdx.x;
  const float* src;
  int moff, N;
  if (b < 192) {
    int m = b >> 6;
    src = W1 + m * 16384;
    moff = m * 16384;
    N = 128;
    b &= 63;
  } else if (b < 384) {
    int m = (b - 192) >> 6;
    src = W2 + m * 16384;
    moff = (3 + m) * 16384;
    N = 128;
    b = (b - 192) & 63;
  } else if (b < 448) {
    src = fW1;
    moff = 6 * 16384;
    N = 128;
    b -= 384;
  } else {
    src = fW2;
    moff = 7 * 16384;
    N = 64;
    b -= 448;
  }
  int idx = b * 256 + threadIdx.x;  // n*128 + k
  int n = idx >> 7, k = idx & 127;
  if (n < N) wt[moff + idx] = f2b(src[(size_t)k * N + n]);
}

// ---------- gather-reduce: h16[node] = x16[node] + sum_{s in in(node)} x16[s] ----------
// 16 threads/node, 8 cols each; unroll-4 independent accumulators.
// csr nt-load (single-use stream), h16 nt-store (not re-read here) -> keep the
// 25.6MB x16 gather table L2-resident.
__global__ __launch_bounds__(256) void gather_k(const int* __restrict__ cnt,
                                                const int* __restrict__ csr,
                                                const unsigned short* __restrict__ x16,
                                                unsigned short* __restrict__ h16) {
  const int node = blockIdx.x * 16 + (threadIdx.x >> 4);
  const int l = threadIdx.x & 15;
  const int beg = node * CAP;
  const int end = beg + cnt[node];
  V8 v;
  v.u4 = *(const uint4*)(x16 + (size_t)node * DD + l * 8);
  float a0[8], a1[8], a2[8], a3[8];
#pragma unroll
  for (int j = 0; j < 8; ++j) {
    a0[j] = b2f(v.us[j]);
    a1[j] = 0.f;
    a2[j] = 0.f;
    a3[j] = 0.f;
  }
  int p = beg;
  for (; p + 4 <= end; p += 4) {
    const int s0 = __builtin_nontemporal_load(&csr[p]);
    const int s1 = __builtin_nontemporal_load(&csr[p + 1]);
    const int s2 = __builtin_nontemporal_load(&csr[p + 2]);
    const int s3 = __builtin_nontemporal_load(&csr[p + 3]);
    V8 w0, w1, w2, w3;
    w0.u4 = *(const uint4*)(x16 + (size_t)s0 * DD + l * 8);
    w1.u4 = *(const uint4*)(x16 + (size_t)s1 * DD + l * 8);
    w2.u4 = *(const uint4*)(x16 + (size_t)s2 * DD + l * 8);
    w3.u4 = *(const uint4*)(x16 + (size_t)s3 * DD + l * 8);
#pragma unroll
    for (int j = 0; j < 8; ++j) {
      a0[j] += b2f(w0.us[j]);
      a1[j] += b2f(w1.us[j]);
      a2[j] += b2f(w2.us[j]);
      a3[j] += b2f(w3.us[j]);
    }
  }
  for (; p < end; ++p) {
    const int s0 = __builtin_nontemporal_load(&csr[p]);
    V8 w0;
    w0.u4 = *(const uint4*)(x16 + (size_t)s0 * DD + l * 8);
#pragma unroll
    for (int j = 0; j < 8; ++j) a0[j] += b2f(w0.us[j]);
  }
  V8 o;
#pragma unroll
  for (int j = 0; j < 8; ++j) o.us[j] = f2b((a0[j] + a1[j]) + (a2[j] + a3[j]));
  __builtin_nontemporal_store(o.v4, (v4u*)(h16 + (size_t)node * DD + l * 8));
}

// ---------- MFMA GEMM, grid-stride over row-tiles ----------
// C[M x NCOLS] = A[M x 128] @ wT^T + bias; wT pre-transposed bf16 [NCOLS][128].
// Each block stages weights in LDS ONCE, then loops 64-row tiles (3 per block).
// AMODE: 1 = A bf16 plain, 2 = A bf16 + BN(scale,shift from raw stats)+ReLU
// EPI:   0 = store bf16, 1 = relu + store bf16, 2 = store fp32
// STATS: 1 = accumulate per-column sum/sumsq of the (rounded) output into stats_out
template <int AMODE, int NCOLS, int EPI, int STATS>
__global__ __launch_bounds__(256) void gemm_k(const unsigned short* __restrict__ Aptr,
                                              const unsigned short* __restrict__ wT,
                                              const float* __restrict__ bias,
                                              const float* __restrict__ bn_stats,
                                              const float* __restrict__ gamma,
                                              const float* __restrict__ beta,
                                              void* __restrict__ Cptr,
                                              float* __restrict__ stats_out) {
  __shared__ unsigned short bT[NCOLS][136];  // 16B-aligned rows, benign 2-way alias
  __shared__ float biasS[NCOLS];
  __shared__ float scS[128];
  __shared__ float shS[128];
  __shared__ float sS[NCOLS];
  __shared__ float s2S[NCOLS];
  const int tid = threadIdx.x;

  for (int i = tid; i < NCOLS * 16; i += 256) {
    int n = i >> 4, k8 = (i & 15) << 3;
    *(uint4*)&bT[n][k8] = *(const uint4*)(wT + n * 128 + k8);
  }
  if (tid < NCOLS) biasS[tid] = bias[tid];
  if (AMODE == 2 && tid < 128) {
    const float inv_n = 1.0f / (float)NN;
    float mu = bn_stats[tid] * inv_n;
    float var = bn_stats[128 + tid] * inv_n - mu * mu;
    float sc = gamma[tid] * rsqrtf(var + 1e-5f);
    scS[tid] = sc;
    shS[tid] = beta[tid] - mu * sc;
  }
  if (STATS && tid < NCOLS) {
    sS[tid] = 0.f;
    s2S[tid] = 0.f;
  }
  __syncthreads();

  const int wv = tid >> 6;
  const int lane = tid & 63;
  const int l16 = lane & 15;
  const int quad = lane >> 4;

  for (int tile = blockIdx.x; tile < TILES; tile += gridDim.x) {
    const int arow = tile * 64 + wv * 16 + l16;  // A row (m = lane&15)
    const bool rv = arow < NN;

    V8 afs[4];
#pragma unroll
    for (int kc = 0; kc < 4; ++kc) {
      const int k0 = kc * 32 + quad * 8;
      afs[kc].u4 = rv ? *(const uint4*)(Aptr + (size_t)arow * DD + k0)
                      : make_uint4(0u, 0u, 0u, 0u);
      if (AMODE == 2) {
#pragma unroll
        for (int j = 0; j < 8; ++j) {
          float f = fmaf(b2f(afs[kc].us[j]), scS[k0 + j], shS[k0 + j]);
          afs[kc].us[j] = f2b(fmaxf(f, 0.0f));
        }
      }
    }

    f32x4 acc[NCOLS / 16];
#pragma unroll
    for (int nt = 0; nt < NCOLS / 16; ++nt) acc[nt] = (f32x4)(0.0f);
#pragma unroll
    for (int kc = 0; kc < 4; ++kc) {
      const int k0 = kc * 32 + quad * 8;
#pragma unroll
      for (int nt = 0; nt < NCOLS / 16; ++nt) {
        V8 bf;
        bf.u4 = *(const uint4*)&bT[nt * 16 + l16][k0];
        acc[nt] =
            __builtin_amdgcn_mfma_f32_16x16x32_bf16(afs[kc].s8, bf.s8, acc[nt], 0, 0, 0);
      }
    }

    // C/D layout: col = lane&15, row = quad*4 + reg
    const int r0 = tile * 64 + wv * 16 + quad * 4;
#pragma unroll
    for (int nt = 0; nt < NCOLS / 16; ++nt) {
      const int col = nt * 16 + l16;
      const float bv = biasS[col];
      float s = 0.f, s2 = 0.f;
#pragma unroll
      for (int i = 0; i < 4; ++i) {
        const int r = r0 + i;
        if (r < NN) {
          float v = acc[nt][i] + bv;
          if (EPI == 1) v = fmaxf(v, 0.0f);
          if (EPI == 2) {
            ((float*)Cptr)[(size_t)r * NCOLS + col] = v;
          } else {
            unsigned short us = f2b(v);
            ((unsigned short*)Cptr)[(size_t)r * NCOLS + col] = us;
            if (STATS) {
              float vr = b2f(us);  // stats on rounded value (matches gemm2's input)
              s += vr;
              s2 += vr * vr;
            }
          }
        }
      }
      if (STATS) {
        s += __shfl_xor(s, 16);
        s += __shfl_xor(s, 32);
        s2 += __shfl_xor(s2, 16);
        s2 += __shfl_xor(s2, 32);
        if (quad == 0) {
          atomicAdd(&sS[col], s);
          atomicAdd(&s2S[col], s2);
        }
      }
    }
  }

  if (STATS) {
    __syncthreads();
    if (tid < NCOLS) {
      atomicAdd(&stats_out[tid], sS[tid]);
      atomicAdd(&stats_out[128 + tid], s2S[tid]);
    }
  }
}

// ---------- launch ----------
extern "C" void kernel_launch(void* const* d_in, const int* in_sizes, int n_in,
                              void* d_out, int out_size, void* d_ws, size_t ws_size,
                              hipStream_t stream) {
  const float* x = (const float*)d_in[0];
  const int* ei = (const int*)d_in[1];
  const float* W1 = (const float*)d_in[2];
  const float* b1 = (const float*)d_in[3];
  const float* g1 = (const float*)d_in[4];
  const float* be1 = (const float*)d_in[5];
  const float* W2 = (const float*)d_in[6];
  const float* b2 = (const float*)d_in[7];
  const float* fW1 = (const float*)d_in[8];
  const float* fb1 = (const float*)d_in[9];
  const float* fg1 = (const float*)d_in[10];
  const float* fbe1 = (const float*)d_in[11];
  const float* fW2 = (const float*)d_in[12];
  const float* fb2 = (const float*)d_in[13];

  char* ws = (char*)d_ws;
  unsigned short* x16 = (unsigned short*)ws;                       // 25.6 MB
  unsigned short* t16 = (unsigned short*)(ws + (size_t)25600000);  // 25.6 MB
  int* packed = (int*)t16;  // 12.8 MB, consumed by scatter before t16 is written
  int* csr = (int*)(ws + (size_t)51200000);         // NN*CAP*4 = 25.6 MB
  int* cnt = (int*)(ws + (size_t)76800000);         // 400 KB
  float* stats4 = (float*)(ws + (size_t)77200000);  // 4 x 256 f
  int* flag = (int*)(ws + (size_t)77204992);
  unsigned short* wt = (unsigned short*)(ws + (size_t)77210000);  // 256 KB

  const int vecBlocks = (NN * DD) / (256 * 8);  // 6250
  const int edgeBlocks = NE / 256;              // 6250
  const int filtBlocks = NGROUP * 8;            // 2048
  const int nodeBlocks = NN / 16;               // 6250

  detect_k<<<1, 64, 0, stream>>>(ei, flag);
  (void)hipMemsetAsync(stats4, 0, 4 * 256 * sizeof(float), stream);
  cast_k<<<vecBlocks, 256, 0, stream>>>(x, x16);
  pack_k<<<edgeBlocks, 256, 0, stream>>>(ei, packed, cnt, flag);
  wprep_k<<<480, 256, 0, stream>>>(W1, W2, fW1, fW2, wt);
  scatter_k<<<filtBlocks, 256, 0, stream>>>((const long long*)packed, cnt, csr);

  unsigned short* h16 = (unsigned short*)d_out;  // 25.6 MB scratch until final store

  for (int l = 0; l < 3; ++l) {
    gather_k<<<nodeBlocks, 256, 0, stream>>>(cnt, csr, x16, h16);
    gemm_k<1, 128, 0, 1><<<GEMMGRID, 256, 0, stream>>>(
        h16, wt + (size_t)l * 16384, b1 + l * 128, nullptr, nullptr, nullptr, t16,
        stats4 + l * 256);
    gemm_k<2, 128, 1, 0><<<GEMMGRID, 256, 0, stream>>>(
        t16, wt + (size_t)(3 + l) * 16384, b2 + l * 128, stats4 + l * 256,
        g1 + l * 128, be1 + l * 128, x16, nullptr);
  }

  // final MLP: Linear -> BN -> ReLU -> Linear, out fp32 [NN x 64]
  gemm_k<1, 128, 0, 1><<<GEMMGRID, 256, 0, stream>>>(
      x16, wt + (size_t)6 * 16384, fb1, nullptr, nullptr, nullptr, t16,
      stats4 + 3 * 256);
  gemm_k<2, 64, 2, 0><<<GEMMGRID, 256, 0, stream>>>(
      t16, wt + (size_t)7 * 16384, fb2, stats4 + 3 * 256, fg1, fbe1, (float*)d_out,
      nullptr);
}